// Round 1
// baseline (711.440 us; speedup 1.0000x reference)
//
#include <hip/hip_runtime.h>
#include <math.h>

// ---------------------------------------------------------------------------
// TemporalGuidedModule on MI355X, fp32 correctness-first implementation.
//
// All activations kept channel-major [B][C][P] (P = H*W = 16384), which is the
// native [B,C,H,W] layout; 1x1 conv == linear == GEMM Out[o,p] = sum_c W[o,c]*In[c,p].
// Exception: `value` and `msda_out` are pixel-major [B][P][C] so the bilinear
// gather reads contiguous 128B per (head, corner).
// ---------------------------------------------------------------------------

#define PIX 16384   // 128*128 per batch
#define BATCH 2
#define CH 256

// Tiled SGEMM: 128(out) x 128(pix) tile, 256 threads, 8x8 micro-tile.
// IN_PM:  input is pixel-major [P][Cin] (else channel-major [Cin][P])
// OUT_PM: output pixel-major [P][Cout] (else channel-major [Cout][P])
// FUSE: 0 none, 1 x *= in2, 2 x += in2  (in2 channel-major, same shape as in)
template<bool IN_PM, bool OUT_PM, int FUSE, bool RELU>
__global__ __launch_bounds__(256) void gemm_k(
    const float* __restrict__ in, const float* __restrict__ in2,
    const float* __restrict__ W, const float* __restrict__ bias,
    float* __restrict__ out, int Cin, int Cout, int P)
{
  __shared__ __align__(16) float Wt[16][132];  // [kk][oo], padded
  __shared__ __align__(16) float Xt[16][132];  // [kk][pp], padded

  const int tid = threadIdx.x;
  const int tx = tid & 15, ty = tid >> 4;
  const int b  = blockIdx.z;
  const int p0 = blockIdx.x * 128;
  const int o0 = blockIdx.y * 128;

  const float* inb  = in  + (size_t)b * Cin * P;   // same flat size for PM/CM
  const float* in2b = in2 + (size_t)b * Cin * P;
  float*       outb = out + (size_t)b * Cout * P;

  float acc[8][8];
  #pragma unroll
  for (int i = 0; i < 8; ++i)
    #pragma unroll
    for (int j = 0; j < 8; ++j) acc[i][j] = 0.f;

  for (int k0 = 0; k0 < Cin; k0 += 16) {
    { // stage W tile: Wt[kk][oo]
      int kk = tid & 15, ob = tid >> 4;
      #pragma unroll
      for (int it = 0; it < 8; ++it) {
        int oo = ob + 16 * it;
        int o  = o0 + oo;
        Wt[kk][oo] = (o < Cout) ? W[(size_t)o * Cin + k0 + kk] : 0.f;
      }
    }
    if (!IN_PM) { // channel-major input: rows of 128 consecutive pixels
      int pp = tid & 127, kb = tid >> 7;
      #pragma unroll
      for (int it = 0; it < 8; ++it) {
        int kk = kb + 2 * it;
        size_t gi = (size_t)(k0 + kk) * P + p0 + pp;
        float x = inb[gi];
        if (FUSE == 1) x *= in2b[gi];
        if (FUSE == 2) x += in2b[gi];
        Xt[kk][pp] = x;
      }
    } else {      // pixel-major input
      int kk = tid & 15, pb = tid >> 4;
      #pragma unroll
      for (int it = 0; it < 8; ++it) {
        int pp = pb + 16 * it;
        Xt[kk][pp] = inb[(size_t)(p0 + pp) * Cin + k0 + kk];
      }
    }
    __syncthreads();

    const int ai = OUT_PM ? tx : ty;  // indexes o-dimension fragments
    const int bi = OUT_PM ? ty : tx;  // indexes p-dimension fragments
    #pragma unroll
    for (int kk = 0; kk < 16; ++kk) {
      float a[8], x[8];
      *(float4*)&a[0] = *(const float4*)&Wt[kk][ai * 4];
      *(float4*)&a[4] = *(const float4*)&Wt[kk][64 + ai * 4];
      *(float4*)&x[0] = *(const float4*)&Xt[kk][bi * 4];
      *(float4*)&x[4] = *(const float4*)&Xt[kk][64 + bi * 4];
      #pragma unroll
      for (int i = 0; i < 8; ++i)
        #pragma unroll
        for (int j = 0; j < 8; ++j)
          acc[i][j] = fmaf(a[i], x[j], acc[i][j]);
    }
    __syncthreads();
  }

  // epilogue: bias (+relu), vectorized stores
  const int ai = OUT_PM ? tx : ty;
  const int bi = OUT_PM ? ty : tx;
  if (!OUT_PM) {
    #pragma unroll
    for (int i = 0; i < 8; ++i) {
      int o = o0 + (i >> 2) * 64 + ai * 4 + (i & 3);
      if (o < Cout) {
        float bv = bias[o];
        #pragma unroll
        for (int ju = 0; ju < 2; ++ju) {
          float4 v;
          v.x = acc[i][ju * 4 + 0] + bv;
          v.y = acc[i][ju * 4 + 1] + bv;
          v.z = acc[i][ju * 4 + 2] + bv;
          v.w = acc[i][ju * 4 + 3] + bv;
          if (RELU) {
            v.x = fmaxf(v.x, 0.f); v.y = fmaxf(v.y, 0.f);
            v.z = fmaxf(v.z, 0.f); v.w = fmaxf(v.w, 0.f);
          }
          *(float4*)&outb[(size_t)o * P + p0 + ju * 64 + bi * 4] = v;
        }
      }
    }
  } else {
    #pragma unroll
    for (int j = 0; j < 8; ++j) {
      int p = p0 + (j >> 2) * 64 + bi * 4 + (j & 3);
      #pragma unroll
      for (int iu = 0; iu < 2; ++iu) {
        int ob = o0 + iu * 64 + ai * 4;
        if (ob < Cout) {
          float4 v;
          v.x = acc[iu * 4 + 0][j] + bias[ob + 0];
          v.y = acc[iu * 4 + 1][j] + bias[ob + 1];
          v.z = acc[iu * 4 + 2][j] + bias[ob + 2];
          v.w = acc[iu * 4 + 3][j] + bias[ob + 3];
          if (RELU) {
            v.x = fmaxf(v.x, 0.f); v.y = fmaxf(v.y, 0.f);
            v.z = fmaxf(v.z, 0.f); v.w = fmaxf(v.w, 0.f);
          }
          *(float4*)&outb[(size_t)p * Cout + ob] = v;
        }
      }
    }
  }
}

// Softmax over NP=8 points per (b, pixel, head); logits channel-major [B][64][P],
// in-place. One thread per (b,p,h); p fastest -> coalesced row reads.
__global__ __launch_bounds__(256) void softmax8_k(float* __restrict__ a)
{
  int t = blockIdx.x * 256 + threadIdx.x;     // 0 .. 2*8*PIX-1
  int p = t & (PIX - 1);
  int h = (t >> 14) & 7;
  int b = t >> 17;
  float* base = a + ((size_t)b * 64 + h * 8) * PIX + p;
  float v[8];
  float m = -1e30f;
  #pragma unroll
  for (int i = 0; i < 8; ++i) { v[i] = base[(size_t)i * PIX]; m = fmaxf(m, v[i]); }
  float s = 0.f;
  #pragma unroll
  for (int i = 0; i < 8; ++i) { v[i] = expf(v[i] - m); s += v[i]; }
  float inv = 1.f / s;
  #pragma unroll
  for (int i = 0; i < 8; ++i) base[(size_t)i * PIX] = v[i] * inv;
}

// MSDA bilinear gather. One thread per (b,q,h,d): out flat index == global tid.
// value/out pixel-major [B][P][256]; offs [B][128][P] cm; attn [B][64][P] cm.
__global__ __launch_bounds__(256) void msda_k(
    const float* __restrict__ value, const float* __restrict__ offs,
    const float* __restrict__ attn, float* __restrict__ out)
{
  int t = blockIdx.x * 256 + threadIdx.x;
  int d = t & 31;
  int h = (t >> 5) & 7;
  int pg = t >> 8;             // b*PIX + p
  int b = pg >> 14;
  int p = pg & (PIX - 1);
  int px = p & 127, py = p >> 7;

  const float* vb = value + (size_t)b * PIX * 256;
  const float* ob = offs  + (size_t)b * 128 * PIX;
  const float* ab = attn  + (size_t)b * 64 * PIX;

  float acc = 0.f;
  #pragma unroll
  for (int pt = 0; pt < 8; ++pt) {
    int c = h * 8 + pt;
    float ox = ob[(size_t)(2 * c + 0) * PIX + p];
    float oy = ob[(size_t)(2 * c + 1) * PIX + p];
    float aw = ab[(size_t)c * PIX + p];
    // ix = loc_x*W - 0.5 collapses to px + ox (the 0.5s cancel)
    float ix = px + ox, iy = py + oy;
    float x0f = floorf(ix), y0f = floorf(iy);
    float fx = ix - x0f, fy = iy - y0f;
    int x0 = (int)x0f, y0 = (int)y0f;

    auto corner = [&](int xx, int yy, float w) -> float {
      bool valid = ((unsigned)xx < 128u) & ((unsigned)yy < 128u);
      int xc = min(max(xx, 0), 127), yc = min(max(yy, 0), 127);
      float v = vb[((size_t)(yc * 128 + xc)) * 256 + h * 32 + d];
      return valid ? w * v : 0.f;
    };
    float s = corner(x0,     y0,     (1.f - fx) * (1.f - fy))
            + corner(x0 + 1, y0,     fx * (1.f - fy))
            + corner(x0,     y0 + 1, (1.f - fx) * fy)
            + corner(x0 + 1, y0 + 1, fx * fy);
    acc = fmaf(aw, s, acc);
  }
  out[t] = acc;
}

extern "C" void kernel_launch(void* const* d_in, const int* in_sizes, int n_in,
                              void* d_out, int out_size, void* d_ws, size_t ws_size,
                              hipStream_t stream)
{
  const float* xt     = (const float*)d_in[0];
  const float* xt_1   = (const float*)d_in[1];
  const float* W_in1  = (const float*)d_in[2];
  const float* b_in1  = (const float*)d_in[3];
  const float* W_in2  = (const float*)d_in[4];
  const float* b_in2  = (const float*)d_in[5];
  const float* Wv     = (const float*)d_in[6];
  const float* bv     = (const float*)d_in[7];
  const float* Ws     = (const float*)d_in[8];
  const float* bs_off = (const float*)d_in[9];
  const float* Wa     = (const float*)d_in[10];
  const float* ba     = (const float*)d_in[11];
  const float* Wo     = (const float*)d_in[12];
  const float* bo     = (const float*)d_in[13];
  const float* Wt1    = (const float*)d_in[14];
  const float* bt1    = (const float*)d_in[15];
  const float* Wt2    = (const float*)d_in[16];
  const float* bt2    = (const float*)d_in[17];
  const float* Wout   = (const float*)d_in[18];
  const float* bout   = (const float*)d_in[19];

  const int P = PIX;
  float* ws = (float*)d_ws;
  const size_t full = (size_t)BATCH * CH * P;      // 8.39M floats
  float* x1   = ws;                   // x1 (live to the end)
  float* r1   = ws + full;            // x2 -> msda_out -> h1
  float* r2   = ws + 2 * full;        // value -> xt_star -> tg
  float* offs = ws + 3 * full;        // [B][128][P]
  float* attn = ws + 3 * full + (size_t)BATCH * 128 * P;  // [B][64][P]

  dim3 blk(256);
  dim3 gFull(P / 128, 2, BATCH);   // Cout=256
  dim3 gHalf(P / 128, 1, BATCH);   // Cout=128 or 64 (guarded)

  // 1,2: input projections (channel-major out)
  gemm_k<false,false,0,false><<<gFull, blk, 0, stream>>>(xt,   xt,   W_in1, b_in1, x1, CH, CH, P);
  gemm_k<false,false,0,false><<<gFull, blk, 0, stream>>>(xt_1, xt_1, W_in2, b_in2, r1, CH, CH, P);
  // 3: value projection, pixel-major out
  gemm_k<false,true ,0,false><<<gFull, blk, 0, stream>>>(r1, r1, Wv, bv, r2, CH, CH, P);
  // 4: sampling offsets (Cout=128), 5: attention logits (Cout=64)
  gemm_k<false,false,0,false><<<gHalf, blk, 0, stream>>>(x1, x1, Ws, bs_off, offs, CH, 128, P);
  gemm_k<false,false,0,false><<<gHalf, blk, 0, stream>>>(x1, x1, Wa, ba,     attn, CH, 64,  P);
  // 6: softmax over 8 points
  softmax8_k<<<dim3((BATCH * 8 * P) / 256), blk, 0, stream>>>(attn);
  // 7: deformable attention gather -> pixel-major [B][P][256] (over x2)
  msda_k<<<dim3((BATCH * P * 256) / 256), blk, 0, stream>>>(r2, offs, attn, r1);
  // 8: output projection Wo (pixel-major in, channel-major out) -> xt_star (over value)
  gemm_k<true ,false,0,false><<<gFull, blk, 0, stream>>>(r1, r1, Wo, bo, r2, CH, CH, P);
  // 9: h1 = relu(Wt1 @ (x1 * xt_star)) (mul fused into staging)
  gemm_k<false,false,1,true ><<<gFull, blk, 0, stream>>>(r2, x1, Wt1, bt1, r1, CH, CH, P);
  // 10: tg = Wt2 @ h1
  gemm_k<false,false,0,false><<<gFull, blk, 0, stream>>>(r1, r1, Wt2, bt2, r2, CH, CH, P);
  // 11: out = relu(Wout @ (x1 + tg)) (add fused into staging)
  gemm_k<false,false,2,true ><<<gFull, blk, 0, stream>>>(r2, x1, Wout, bout, (float*)d_out, CH, CH, P);
}

// Round 2
// 257.368 us; speedup vs baseline: 2.7643x; 2.7643x over previous
//
#include <hip/hip_runtime.h>
#include <math.h>

// ---------------------------------------------------------------------------
// TemporalGuidedModule, round 2: bf16 MFMA GEMMs + vectorized fused MSDA.
//
// Data layout strategy: all intermediate activations are PIXEL-MAJOR bf16
// [B][P][C] (P = 16384). Then for GEMM Out[p][o] = sum_k X[p][k] * W[o][k]:
//   A-operand (X) rows are k-contiguous, B-operand (W[o][k]) rows are
//   k-contiguous -> no LDS transpose needed for either MFMA operand.
// Channel-major fp32 is used only at the boundaries (xt/xt_1 inputs via a
// transpose-convert prepass; offs/attn logits + final d_out via the direct
// float4 channel-major epilogue).
// ---------------------------------------------------------------------------

#define PIX 16384
#define BATCH 2
#define CH 256

typedef short bf16x8 __attribute__((ext_vector_type(8)));
typedef float f32x4 __attribute__((ext_vector_type(4)));

__device__ __forceinline__ ushort f2bf(float f) {
  union { float f; unsigned u; } v; v.f = f;
  unsigned u = v.u;
  unsigned r = u + 0x7fffu + ((u >> 16) & 1u);   // RNE
  return (ushort)(r >> 16);
}
__device__ __forceinline__ float bf2f(ushort s) {
  union { unsigned u; float f; } v; v.u = ((unsigned)s) << 16;
  return v.f;
}

// --------------------------------------------------------------------------
// Transpose-convert: [B][C][P] f32 -> [B][P][C] bf16.
// --------------------------------------------------------------------------
__global__ __launch_bounds__(256) void tconv_k(const float* __restrict__ in,
                                               ushort* __restrict__ out)
{
  __shared__ float t[32][33];
  const int tid = threadIdx.x;
  const int b = blockIdx.z;
  const int p0 = blockIdx.x * 32, c0 = blockIdx.y * 32;
  const int tx = tid & 31, ty = tid >> 5;
  const float* inb = in + (size_t)b * CH * PIX;
  #pragma unroll
  for (int i = 0; i < 4; ++i)
    t[ty + i * 8][tx] = inb[(size_t)(c0 + ty + i * 8) * PIX + p0 + tx];
  __syncthreads();
  const int cx = (tid & 15) * 2, py = tid >> 4;
  ushort* outb = out + (size_t)b * PIX * CH;
  #pragma unroll
  for (int i = 0; i < 2; ++i) {
    int pl = py + i * 16;
    unsigned lo = f2bf(t[cx][pl]);
    unsigned hi = f2bf(t[cx + 1][pl]);
    *(unsigned*)(outb + (size_t)(p0 + pl) * CH + c0 + cx) = lo | (hi << 16);
  }
}

// --------------------------------------------------------------------------
// MFMA GEMM: Out[p][o] = sum_k X[p][k]*W[o][k] + b[o]
//   X: pixel-major bf16 [B][P][256]; W: fp32 [Cout][256] (converted on the fly)
//   Tile 128p x 128o, BK=32, 4 waves (2x2), wave tile 64x64 (4x4 16x16x32 frags)
//   OUT_PM: bf16 pixel-major out (LDS-bounce epilogue); else fp32 channel-major
//   FUSE: 0 none, 1 x*=in2, 2 x+=in2 (in2 pixel-major bf16)
// --------------------------------------------------------------------------
template<int FUSE, bool RELU, bool OUT_PM>
__global__ __launch_bounds__(256) void gemm_mfma_k(
    const ushort* __restrict__ in, const ushort* __restrict__ in2,
    const float* __restrict__ W, const float* __restrict__ bias,
    void* __restrict__ out, int Cout)
{
  __shared__ char smem[34816];           // union: stage X[128][40]+W[128][40] bf16 | epi [128][136] bf16
  const int tid = threadIdx.x;
  const int b = blockIdx.z;
  const int p0 = blockIdx.x * 128;
  const int o0 = blockIdx.y * 128;

  const ushort* inb = in + (size_t)b * PIX * CH;

  const int sr = tid >> 1;               // staging row 0..127
  const int sh = (tid & 1) * 16;         // k-half: 0 or 16

  const ushort* xrow = inb + (size_t)(p0 + sr) * CH + sh;
  const ushort* x2row = (FUSE != 0) ? (in2 + (size_t)b * PIX * CH + (size_t)(p0 + sr) * CH + sh)
                                    : (const ushort*)nullptr;
  const bool wvalid = (o0 + sr) < Cout;
  const float* wrow = W + (size_t)(wvalid ? (o0 + sr) : 0) * CH + sh;

  char* xdst = smem + sr * 80 + sh * 2;
  char* wdst = smem + 10240 + sr * 80 + sh * 2;

  const int l = tid & 63, wid = tid >> 6;
  const int wm = wid >> 1, wn = wid & 1;
  const int lr = l & 15, g = l >> 4;

  f32x4 acc[4][4];
  #pragma unroll
  for (int i = 0; i < 4; ++i)
    #pragma unroll
    for (int j = 0; j < 4; ++j)
      acc[i][j] = (f32x4){0.f, 0.f, 0.f, 0.f};

  for (int ks = 0; ks < 8; ++ks) {
    const int k0 = ks * 32;
    // ---- stage X (already bf16 in global) ----
    if (FUSE == 0) {
      uint4 a = *(const uint4*)(xrow + k0);
      uint4 c = *(const uint4*)(xrow + k0 + 8);
      *(uint4*)xdst = a;
      *(uint4*)(xdst + 16) = c;
    } else {
      ushort xa[16], xb[16], r[16];
      *(uint4*)&xa[0] = *(const uint4*)(xrow + k0);
      *(uint4*)&xa[8] = *(const uint4*)(xrow + k0 + 8);
      *(uint4*)&xb[0] = *(const uint4*)(x2row + k0);
      *(uint4*)&xb[8] = *(const uint4*)(x2row + k0 + 8);
      #pragma unroll
      for (int j = 0; j < 16; ++j) {
        float f = (FUSE == 1) ? bf2f(xa[j]) * bf2f(xb[j]) : bf2f(xa[j]) + bf2f(xb[j]);
        r[j] = f2bf(f);
      }
      *(uint4*)xdst = *(uint4*)&r[0];
      *(uint4*)(xdst + 16) = *(uint4*)&r[8];
    }
    // ---- stage W (fp32 -> bf16 convert) ----
    {
      ushort wr[16];
      #pragma unroll
      for (int i = 0; i < 4; ++i) {
        float4 wv = wvalid ? *(const float4*)(wrow + k0 + i * 4)
                           : make_float4(0.f, 0.f, 0.f, 0.f);
        wr[i * 4 + 0] = f2bf(wv.x); wr[i * 4 + 1] = f2bf(wv.y);
        wr[i * 4 + 2] = f2bf(wv.z); wr[i * 4 + 3] = f2bf(wv.w);
      }
      *(uint4*)wdst = *(uint4*)&wr[0];
      *(uint4*)(wdst + 16) = *(uint4*)&wr[8];
    }
    __syncthreads();
    // ---- fragments + MFMA ----
    bf16x8 af[4], bfr[4];
    #pragma unroll
    for (int fm = 0; fm < 4; ++fm)
      af[fm] = *(const bf16x8*)(smem + (size_t)(wm * 64 + fm * 16 + lr) * 80 + g * 16);
    #pragma unroll
    for (int fn = 0; fn < 4; ++fn)
      bfr[fn] = *(const bf16x8*)(smem + 10240 + (size_t)(wn * 64 + fn * 16 + lr) * 80 + g * 16);
    #pragma unroll
    for (int fm = 0; fm < 4; ++fm)
      #pragma unroll
      for (int fn = 0; fn < 4; ++fn)
        acc[fm][fn] = __builtin_amdgcn_mfma_f32_16x16x32_bf16(af[fm], bfr[fn], acc[fm][fn], 0, 0, 0);
    __syncthreads();
  }

  // ---- epilogue ----
  // C/D layout (16x16x32): col(o) = lane&15, row(p) = (lane>>4)*4 + reg
  float bv[4]; bool ov[4]; int ol[4];
  #pragma unroll
  for (int fn = 0; fn < 4; ++fn) {
    ol[fn] = wn * 64 + fn * 16 + lr;
    int o = o0 + ol[fn];
    ov[fn] = o < Cout;
    bv[fn] = ov[fn] ? bias[o] : 0.f;
  }

  if (OUT_PM) {
    ushort* El = (ushort*)smem;          // [128][136]
    #pragma unroll
    for (int fm = 0; fm < 4; ++fm)
      #pragma unroll
      for (int fn = 0; fn < 4; ++fn)
        #pragma unroll
        for (int r = 0; r < 4; ++r) {
          int pl = wm * 64 + fm * 16 + g * 4 + r;
          float v = acc[fm][fn][r] + bv[fn];
          if (RELU) v = fmaxf(v, 0.f);
          El[pl * 136 + ol[fn]] = f2bf(v);
        }
    __syncthreads();
    ushort* outb = (ushort*)out + (size_t)b * PIX * CH;
    const int pr = tid >> 1, hf = tid & 1;
    #pragma unroll
    for (int j = 0; j < 8; ++j) {
      uint4 v = *(uint4*)(smem + pr * 272 + (hf * 64 + j * 8) * 2);
      *(uint4*)(outb + (size_t)(p0 + pr) * CH + o0 + hf * 64 + j * 8) = v;
    }
  } else {
    float* outb = (float*)out + (size_t)b * Cout * PIX;
    #pragma unroll
    for (int fm = 0; fm < 4; ++fm)
      #pragma unroll
      for (int fn = 0; fn < 4; ++fn) {
        if (ov[fn]) {
          float4 v;
          v.x = acc[fm][fn][0] + bv[fn];
          v.y = acc[fm][fn][1] + bv[fn];
          v.z = acc[fm][fn][2] + bv[fn];
          v.w = acc[fm][fn][3] + bv[fn];
          if (RELU) {
            v.x = fmaxf(v.x, 0.f); v.y = fmaxf(v.y, 0.f);
            v.z = fmaxf(v.z, 0.f); v.w = fmaxf(v.w, 0.f);
          }
          *(float4*)(outb + (size_t)(o0 + ol[fn]) * PIX + p0 + wm * 64 + fm * 16 + g * 4) = v;
        }
      }
  }
}

// --------------------------------------------------------------------------
// Fused MSDA: inline softmax over 8 logits + bilinear gather.
// One wave per pixel: lane = h*8 + d4 (8 heads x 8 dim-quads of 4 dims).
// value pm bf16 [B][P][256]; offs cm f32 [B][128][P]; attn logits cm f32
// [B][64][P]; out pm bf16 [B][P][256].
// --------------------------------------------------------------------------
__global__ __launch_bounds__(256) void msda_k(
    const ushort* __restrict__ value, const float* __restrict__ offs,
    const float* __restrict__ attn, ushort* __restrict__ out)
{
  const int t = blockIdx.x * 256 + threadIdx.x;
  const int d4 = t & 7;
  const int h = (t >> 3) & 7;
  const int pg = t >> 6;
  const int b = pg >> 14;
  const int p = pg & (PIX - 1);
  const int px = p & 127, py = p >> 7;

  const ushort* vb = value + (size_t)b * PIX * CH;
  const float* ob = offs + (size_t)b * 128 * PIX;
  const float* ab = attn + (size_t)b * 64 * PIX;

  // inline softmax over the 8 point-logits of this (p,h)
  float lg[8];
  float m = -1e30f;
  #pragma unroll
  for (int i = 0; i < 8; ++i) {
    lg[i] = ab[(size_t)(h * 8 + i) * PIX + p];
    m = fmaxf(m, lg[i]);
  }
  float s = 0.f;
  #pragma unroll
  for (int i = 0; i < 8; ++i) { lg[i] = __expf(lg[i] - m); s += lg[i]; }
  const float inv = 1.f / s;

  float a0 = 0.f, a1 = 0.f, a2 = 0.f, a3 = 0.f;
  #pragma unroll
  for (int pt = 0; pt < 8; ++pt) {
    const int c = h * 8 + pt;
    const float ox = ob[(size_t)(2 * c) * PIX + p];
    const float oy = ob[(size_t)(2 * c + 1) * PIX + p];
    const float aw = lg[pt] * inv;
    // loc*W - 0.5 collapses: ix = px + ox, iy = py + oy
    const float ix = px + ox, iy = py + oy;
    const float xf = floorf(ix), yf = floorf(iy);
    const float fx = ix - xf, fy = iy - yf;
    const int x0 = (int)xf, y0 = (int)yf;

    #pragma unroll
    for (int cr = 0; cr < 4; ++cr) {
      const int dx = cr & 1, dy = cr >> 1;
      const int xx = x0 + dx, yy = y0 + dy;
      const float wx = dx ? fx : (1.f - fx);
      const float wy = dy ? fy : (1.f - fy);
      const bool valid = ((unsigned)xx < 128u) & ((unsigned)yy < 128u);
      float w = valid ? (wx * wy * aw) : 0.f;
      const int xc = min(max(xx, 0), 127), yc = min(max(yy, 0), 127);
      uint2 rv = *(const uint2*)(vb + ((size_t)(yc * 128 + xc) * CH + h * 32 + d4 * 4));
      a0 = fmaf(w, bf2f((ushort)(rv.x & 0xffffu)), a0);
      a1 = fmaf(w, bf2f((ushort)(rv.x >> 16)), a1);
      a2 = fmaf(w, bf2f((ushort)(rv.y & 0xffffu)), a2);
      a3 = fmaf(w, bf2f((ushort)(rv.y >> 16)), a3);
    }
  }
  unsigned lo = (unsigned)f2bf(a0) | ((unsigned)f2bf(a1) << 16);
  unsigned hi = (unsigned)f2bf(a2) | ((unsigned)f2bf(a3) << 16);
  uint2 r; r.x = lo; r.y = hi;
  *(uint2*)(out + ((size_t)pg * CH + h * 32 + d4 * 4)) = r;
}

extern "C" void kernel_launch(void* const* d_in, const int* in_sizes, int n_in,
                              void* d_out, int out_size, void* d_ws, size_t ws_size,
                              hipStream_t stream)
{
  const float* xt     = (const float*)d_in[0];
  const float* xt_1   = (const float*)d_in[1];
  const float* W_in1  = (const float*)d_in[2];
  const float* b_in1  = (const float*)d_in[3];
  const float* W_in2  = (const float*)d_in[4];
  const float* b_in2  = (const float*)d_in[5];
  const float* Wv     = (const float*)d_in[6];
  const float* bv     = (const float*)d_in[7];
  const float* Ws     = (const float*)d_in[8];
  const float* bs_off = (const float*)d_in[9];
  const float* Wa     = (const float*)d_in[10];
  const float* ba     = (const float*)d_in[11];
  const float* Wo     = (const float*)d_in[12];
  const float* bo     = (const float*)d_in[13];
  const float* Wt1    = (const float*)d_in[14];
  const float* bt1    = (const float*)d_in[15];
  const float* Wt2    = (const float*)d_in[16];
  const float* bt2    = (const float*)d_in[17];
  const float* Wout   = (const float*)d_in[18];
  const float* bout   = (const float*)d_in[19];

  char* ws = (char*)d_ws;
  const size_t SLOT = (size_t)BATCH * PIX * CH * 2;   // 16 MB bf16 tensor
  ushort* s0 = (ushort*)(ws + 0 * SLOT);   // xt_pm   -> xt_star
  ushort* s1 = (ushort*)(ws + 1 * SLOT);   // xt1_pm  -> h1
  ushort* s2 = (ushort*)(ws + 2 * SLOT);   // x1 (live to end)
  ushort* s3 = (ushort*)(ws + 3 * SLOT);   // x2      -> tg
  ushort* s4 = (ushort*)(ws + 4 * SLOT);   // value
  ushort* s5 = (ushort*)(ws + 5 * SLOT);   // msda_out
  float* offs_f = (float*)(ws + 6 * SLOT);                       // [B][128][P] f32
  float* attn_f = (float*)(ws + 6 * SLOT + (size_t)BATCH * 128 * PIX * 4);  // [B][64][P] f32

  dim3 blk(256);
  dim3 gT(PIX / 32, CH / 32, BATCH);
  dim3 gFull(PIX / 128, 2, BATCH);
  dim3 gHalf(PIX / 128, 1, BATCH);

  // input projections (via transpose-convert prepass)
  tconv_k<<<gT, blk, 0, stream>>>(xt, s0);
  tconv_k<<<gT, blk, 0, stream>>>(xt_1, s1);
  gemm_mfma_k<0, false, true ><<<gFull, blk, 0, stream>>>(s0, nullptr, W_in1, b_in1, s2, 256); // x1
  gemm_mfma_k<0, false, true ><<<gFull, blk, 0, stream>>>(s1, nullptr, W_in2, b_in2, s3, 256); // x2
  gemm_mfma_k<0, false, true ><<<gFull, blk, 0, stream>>>(s3, nullptr, Wv, bv, s4, 256);       // value
  gemm_mfma_k<0, false, false><<<gHalf, blk, 0, stream>>>(s2, nullptr, Ws, bs_off, offs_f, 128);
  gemm_mfma_k<0, false, false><<<gHalf, blk, 0, stream>>>(s2, nullptr, Wa, ba, attn_f, 64);
  // fused softmax + deformable gather
  msda_k<<<dim3((BATCH * PIX * 64) / 256), blk, 0, stream>>>(s4, offs_f, attn_f, s5);
  // output projection + temporal-guidance MLP
  gemm_mfma_k<0, false, true ><<<gFull, blk, 0, stream>>>(s5, nullptr, Wo, bo, s0, 256);       // xt_star
  gemm_mfma_k<1, true , true ><<<gFull, blk, 0, stream>>>(s0, s2, Wt1, bt1, s1, 256);          // h1 = relu(Wt1@(x1*xt_star))
  gemm_mfma_k<0, false, true ><<<gFull, blk, 0, stream>>>(s1, nullptr, Wt2, bt2, s3, 256);     // tg
  gemm_mfma_k<2, true , false><<<gFull, blk, 0, stream>>>(s3, s2, Wout, bout, d_out, 256);     // relu(Wout@(x1+tg))
}

// Round 4
// 194.977 us; speedup vs baseline: 3.6488x; 1.3200x over previous
//
#include <hip/hip_runtime.h>
#include <math.h>

// ---------------------------------------------------------------------------
// TemporalGuidedModule round 4 (= round 3 + epilogue fix):
//  - 7 GEMMs: Wv@W_in2 composited on device; [Ws;Wa] concatenated.
//  - GEMM: 128x64 tile, BK=64, dbuf LDS + XOR-swizzle (conflict-free b128),
//    single barrier per K-step, 1024 blocks (12 waves/CU).
//  - msda: thread per (pixel, head, 16 dims); sample-major f32 offs/attn.
//  - FIX vs r3: OMODE 0 bounce copy-out was j<2 (covered only half the
//    columns); now j<4 covering all 64 halves per row.
// ---------------------------------------------------------------------------

#define PIX 16384
#define BATCH 2
#define CH 256

typedef short bf16x8 __attribute__((ext_vector_type(8)));
typedef float f32x4 __attribute__((ext_vector_type(4)));

__device__ __forceinline__ ushort f2bf(float f) {
  union { float f; unsigned u; } v; v.f = f;
  unsigned u = v.u;
  unsigned r = u + 0x7fffu + ((u >> 16) & 1u);   // RNE
  return (ushort)(r >> 16);
}
__device__ __forceinline__ float bfl(unsigned u) {  // low bf16 of word -> f32
  union { unsigned u; float f; } v; v.u = u << 16; return v.f;
}
__device__ __forceinline__ float bfh(unsigned u) {  // high bf16 of word -> f32
  union { unsigned u; float f; } v; v.u = u & 0xffff0000u; return v.f;
}
__device__ __forceinline__ unsigned fuse_u32(unsigned a, unsigned b, bool mul) {
  float rl = mul ? bfl(a) * bfl(b) : bfl(a) + bfl(b);
  float rh = mul ? bfh(a) * bfh(b) : bfh(a) + bfh(b);
  return (unsigned)f2bf(rl) | ((unsigned)f2bf(rh) << 16);
}

// --------------------------------------------------------------------------
// Weight prep: convert 5 square mats + [Ws;Wa] to bf16 rows; copy concat bias.
// --------------------------------------------------------------------------
__global__ __launch_bounds__(256) void wprep_k(
    const float* __restrict__ W_in1, const float* __restrict__ Wo,
    const float* __restrict__ Wt1, const float* __restrict__ Wt2,
    const float* __restrict__ Wout, const float* __restrict__ Ws,
    const float* __restrict__ Wa, const float* __restrict__ bs_off,
    const float* __restrict__ ba, ushort* __restrict__ wb,
    float* __restrict__ bsa)
{
  const int blk = blockIdx.x, k = threadIdx.x;
  if (blk >= 1472) {
    if (k < 128) bsa[k] = bs_off[k];
    else if (k < 192) bsa[k] = ba[k - 128];
    return;
  }
  const float* src;
  if (blk < 256) src = W_in1 + (size_t)blk * 256;
  else if (blk < 512) src = Wo + (size_t)(blk - 256) * 256;
  else if (blk < 768) src = Wt1 + (size_t)(blk - 512) * 256;
  else if (blk < 1024) src = Wt2 + (size_t)(blk - 768) * 256;
  else if (blk < 1280) src = Wout + (size_t)(blk - 1024) * 256;
  else if (blk < 1408) src = Ws + (size_t)(blk - 1280) * 256;
  else src = Wa + (size_t)(blk - 1408) * 256;
  wb[(size_t)blk * 256 + k] = f2bf(src[k]);
}

// Wv' = Wv @ W_in2 (bf16), bv' = Wv @ b_in2 + bv. Block = output row o.
__global__ __launch_bounds__(256) void wvcomp_k(
    const float* __restrict__ Wv, const float* __restrict__ W_in2,
    const float* __restrict__ b_in2, const float* __restrict__ bv,
    ushort* __restrict__ Wvp, float* __restrict__ bvp)
{
  const int o = blockIdx.x, k = threadIdx.x;
  float acc = 0.f;
  #pragma unroll 8
  for (int c = 0; c < 256; ++c)
    acc += Wv[(size_t)o * 256 + c] * W_in2[(size_t)c * 256 + k];
  Wvp[(size_t)o * 256 + k] = f2bf(acc);
  __shared__ float red[256];
  red[k] = Wv[(size_t)o * 256 + k] * b_in2[k];
  __syncthreads();
  for (int s = 128; s > 0; s >>= 1) {
    if (k < s) red[k] += red[k + s];
    __syncthreads();
  }
  if (k == 0) bvp[o] = red[0] + bv[o];
}

// --------------------------------------------------------------------------
// Transpose-convert: [B][C][P] f32 -> [B][P][C] bf16.
// --------------------------------------------------------------------------
__global__ __launch_bounds__(256) void tconv_k(const float* __restrict__ in,
                                               ushort* __restrict__ out)
{
  __shared__ float t[32][33];
  const int tid = threadIdx.x;
  const int b = blockIdx.z;
  const int p0 = blockIdx.x * 32, c0 = blockIdx.y * 32;
  const int tx = tid & 31, ty = tid >> 5;
  const float* inb = in + (size_t)b * CH * PIX;
  #pragma unroll
  for (int i = 0; i < 4; ++i)
    t[ty + i * 8][tx] = inb[(size_t)(c0 + ty + i * 8) * PIX + p0 + tx];
  __syncthreads();
  const int cx = (tid & 15) * 2, py = tid >> 4;
  ushort* outb = out + (size_t)b * PIX * CH;
  #pragma unroll
  for (int i = 0; i < 2; ++i) {
    int pl = py + i * 16;
    unsigned lo = f2bf(t[cx][pl]);
    unsigned hi = f2bf(t[cx + 1][pl]);
    *(unsigned*)(outb + (size_t)(p0 + pl) * CH + c0 + cx) = lo | (hi << 16);
  }
}

// --------------------------------------------------------------------------
// MFMA GEMM: Out[p][o] = sum_k X[p][k]*W[o][k] + bias[o]
// Tile 128p x 64o, BK=64, 256 thr (4 waves, wave = 32p x 64o = 2x4 frags).
// Double-buffered swizzled LDS; single barrier per K-step.
// OMODE 0: pm bf16 out (LDS bounce); 1: cm f32 out; 2: pm f32 out (bounce).
// FUSE 0: none; 1: x*=in2; 2: x+=in2 (in2 pm bf16).
// --------------------------------------------------------------------------
template<int FUSE, bool RELU, int OMODE>
__global__ __launch_bounds__(256, 3) void gemm2_k(
    const ushort* __restrict__ in, const ushort* __restrict__ in2,
    const ushort* __restrict__ Wb, const float* __restrict__ bias,
    void* __restrict__ out, int ldo, size_t obstride)
{
  __shared__ __align__(16) char smem[49152];
  const int tid = threadIdx.x;
  const int b = blockIdx.z;
  const int p0 = blockIdx.x * 128;
  const int o0 = blockIdx.y * 64;

  const ushort* inb = in + (size_t)b * PIX * CH;

  const int spr = tid >> 1, skh = tid & 1;                  // X: row, k-half
  const ushort* xsrc = inb + (size_t)(p0 + spr) * CH + skh * 32;
  const ushort* x2src = (FUSE != 0)
      ? in2 + (size_t)b * PIX * CH + (size_t)(p0 + spr) * CH + skh * 32
      : (const ushort*)nullptr;
  const int xrow = spr * 128, xsw = spr & 7;
  const int swr = tid >> 2, swq = tid & 3;                  // W: row, quarter
  const ushort* wsrc = Wb + (size_t)(o0 + swr) * CH + swq * 16;
  const int wrow = swr * 128, wsw = swr & 7;

  const int l = tid & 63, wv = tid >> 6;
  const int lr = l & 15, g4 = l >> 4;

  f32x4 acc[2][4];
  #pragma unroll
  for (int i = 0; i < 2; ++i)
    #pragma unroll
    for (int j = 0; j < 4; ++j) acc[i][j] = (f32x4){0.f, 0.f, 0.f, 0.f};

  uint4 xr[4], x2r[4], wr[2];

#define LOADT(kb)                                                              \
  {                                                                            \
    _Pragma("unroll")                                                          \
    for (int j = 0; j < 4; ++j) xr[j] = *(const uint4*)(xsrc + (kb) + j * 8);  \
    if (FUSE != 0) {                                                           \
      _Pragma("unroll")                                                        \
      for (int j = 0; j < 4; ++j) x2r[j] = *(const uint4*)(x2src + (kb) + j * 8); \
    }                                                                          \
    _Pragma("unroll")                                                          \
    for (int j = 0; j < 2; ++j) wr[j] = *(const uint4*)(wsrc + (kb) + j * 8);  \
  }

#define WRITET(buf)                                                            \
  {                                                                            \
    char* xb = smem + (buf) * 16384 + xrow;                                    \
    _Pragma("unroll")                                                          \
    for (int j = 0; j < 4; ++j) {                                              \
      uint4 v = xr[j];                                                         \
      if (FUSE != 0) {                                                         \
        unsigned* pa = (unsigned*)&v;                                          \
        const unsigned* pb = (const unsigned*)&x2r[j];                         \
        _Pragma("unroll")                                                      \
        for (int w = 0; w < 4; ++w) pa[w] = fuse_u32(pa[w], pb[w], FUSE == 1); \
      }                                                                        \
      *(uint4*)(xb + (((skh * 4 + j) ^ xsw) * 16)) = v;                        \
    }                                                                          \
    char* wbp = smem + 32768 + (buf) * 8192 + wrow;                            \
    _Pragma("unroll")                                                          \
    for (int j = 0; j < 2; ++j)                                                \
      *(uint4*)(wbp + (((swq * 2 + j) ^ wsw) * 16)) = wr[j];                   \
  }

  LOADT(0)
  WRITET(0)
  __syncthreads();

  for (int t = 0; t < 4; ++t) {
    if (t < 3) LOADT((t + 1) * 64)
    const char* XB = smem + (t & 1) * 16384;
    const char* WB = smem + 32768 + (t & 1) * 8192;
    bf16x8 af[2][2], bfr[4][2];
    #pragma unroll
    for (int fm = 0; fm < 2; ++fm) {
      const int p = wv * 32 + fm * 16 + lr;
      #pragma unroll
      for (int kh = 0; kh < 2; ++kh)
        af[fm][kh] = *(const bf16x8*)(XB + p * 128 + (((kh * 4 + g4) ^ (p & 7)) * 16));
    }
    #pragma unroll
    for (int fn = 0; fn < 4; ++fn) {
      const int o = fn * 16 + lr;
      #pragma unroll
      for (int kh = 0; kh < 2; ++kh)
        bfr[fn][kh] = *(const bf16x8*)(WB + o * 128 + (((kh * 4 + g4) ^ (o & 7)) * 16));
    }
    #pragma unroll
    for (int fm = 0; fm < 2; ++fm)
      #pragma unroll
      for (int fn = 0; fn < 4; ++fn) {
        acc[fm][fn] = __builtin_amdgcn_mfma_f32_16x16x32_bf16(af[fm][0], bfr[fn][0], acc[fm][fn], 0, 0, 0);
        acc[fm][fn] = __builtin_amdgcn_mfma_f32_16x16x32_bf16(af[fm][1], bfr[fn][1], acc[fm][fn], 0, 0, 0);
      }
    if (t < 3) WRITET((t + 1) & 1)
    __syncthreads();
  }
#undef LOADT
#undef WRITET

  // ---- epilogue ---- C/D: col(o) = lr, row(p) = g4*4 + reg
  float bvv[4];
  #pragma unroll
  for (int fn = 0; fn < 4; ++fn) bvv[fn] = bias[o0 + fn * 16 + lr];

  if (OMODE == 1) {               // cm f32 direct
    float* outb = (float*)out + (size_t)b * obstride;
    #pragma unroll
    for (int fm = 0; fm < 2; ++fm)
      #pragma unroll
      for (int fn = 0; fn < 4; ++fn) {
        float4 v;
        v.x = acc[fm][fn][0] + bvv[fn]; v.y = acc[fm][fn][1] + bvv[fn];
        v.z = acc[fm][fn][2] + bvv[fn]; v.w = acc[fm][fn][3] + bvv[fn];
        if (RELU) {
          v.x = fmaxf(v.x, 0.f); v.y = fmaxf(v.y, 0.f);
          v.z = fmaxf(v.z, 0.f); v.w = fmaxf(v.w, 0.f);
        }
        *(float4*)(outb + (size_t)(o0 + fn * 16 + lr) * ldo + p0 + wv * 32 + fm * 16 + g4 * 4) = v;
      }
  } else if (OMODE == 0) {        // pm bf16 via LDS bounce
    ushort* El = (ushort*)smem;   // [128][72] halves, pitch 144B
    #pragma unroll
    for (int fm = 0; fm < 2; ++fm)
      #pragma unroll
      for (int fn = 0; fn < 4; ++fn)
        #pragma unroll
        for (int r = 0; r < 4; ++r) {
          const int p = wv * 32 + fm * 16 + g4 * 4 + r;
          float v = acc[fm][fn][r] + bvv[fn];
          if (RELU) v = fmaxf(v, 0.f);
          El[p * 72 + fn * 16 + lr] = f2bf(v);
        }
    __syncthreads();
    ushort* outb = (ushort*)out + (size_t)b * obstride;
    const int row = tid >> 1, hh = tid & 1;
    #pragma unroll
    for (int j = 0; j < 4; ++j) {
      uint4 v = *(uint4*)(smem + row * 144 + hh * 64 + j * 16);
      *(uint4*)(outb + (size_t)(p0 + row) * ldo + o0 + hh * 32 + j * 8) = v;
    }
  } else {                        // OMODE 2: pm f32 via LDS bounce
    float* El = (float*)smem;     // [128][68] f32, pitch 272B
    #pragma unroll
    for (int fm = 0; fm < 2; ++fm)
      #pragma unroll
      for (int fn = 0; fn < 4; ++fn)
        #pragma unroll
        for (int r = 0; r < 4; ++r) {
          const int p = wv * 32 + fm * 16 + g4 * 4 + r;
          float v = acc[fm][fn][r] + bvv[fn];
          if (RELU) v = fmaxf(v, 0.f);
          El[p * 68 + fn * 16 + lr] = v;
        }
    __syncthreads();
    float* outb = (float*)out + (size_t)b * obstride;
    const int row = tid >> 1, hh = tid & 1;
    #pragma unroll
    for (int j = 0; j < 8; ++j) {
      float4 v = *(float4*)(smem + row * 272 + hh * 128 + j * 16);
      *(float4*)(outb + (size_t)(p0 + row) * ldo + o0 + hh * 32 + j * 4) = v;
    }
  }
}

// --------------------------------------------------------------------------
// Fused MSDA: thread per (pixel, head, 16-dim half).
// value pm bf16 [B][P][256]; sa sample-major f32 [B][P][192]
//   (per pixel: [0,128) offs as [h][pt][2], [128,192) attn logits [h][pt]);
// out pm bf16 [B][P][256].
// --------------------------------------------------------------------------
__global__ __launch_bounds__(256) void msda_k(
    const ushort* __restrict__ value, const float* __restrict__ sa,
    ushort* __restrict__ out)
{
  const int t = blockIdx.x * 256 + threadIdx.x;   // B*P*16
  const int dh = t & 1;
  const int h = (t >> 1) & 7;
  const int pg = t >> 4;
  const int b = pg >> 14;
  const int p = pg & (PIX - 1);
  const int px = p & 127, py = p >> 7;

  const ushort* vb = value + (size_t)b * PIX * CH;
  const float* sp = sa + (size_t)pg * 192;

  float4 la = *(const float4*)(sp + 128 + h * 8);
  float4 lb = *(const float4*)(sp + 128 + h * 8 + 4);
  float lg[8] = {la.x, la.y, la.z, la.w, lb.x, lb.y, lb.z, lb.w};
  float m = lg[0];
  #pragma unroll
  for (int i = 1; i < 8; ++i) m = fmaxf(m, lg[i]);
  float s = 0.f;
  #pragma unroll
  for (int i = 0; i < 8; ++i) { lg[i] = __expf(lg[i] - m); s += lg[i]; }
  const float inv = 1.f / s;

  float of[16];
  #pragma unroll
  for (int j = 0; j < 4; ++j)
    *(float4*)&of[j * 4] = *(const float4*)(sp + h * 16 + j * 4);

  float acc[16];
  #pragma unroll
  for (int i = 0; i < 16; ++i) acc[i] = 0.f;

  #pragma unroll
  for (int pt = 0; pt < 8; ++pt) {
    const float ox = of[2 * pt], oy = of[2 * pt + 1];
    const float aw = lg[pt] * inv;
    const float ix = px + ox, iy = py + oy;   // grid_sample -0.5 cancels
    const float xf = floorf(ix), yf = floorf(iy);
    const float fx = ix - xf, fy = iy - yf;
    const int x0 = (int)xf, y0 = (int)yf;
    #pragma unroll
    for (int cr = 0; cr < 4; ++cr) {
      const int dx = cr & 1, dy = cr >> 1;
      const int xx = x0 + dx, yy = y0 + dy;
      const float wx = dx ? fx : (1.f - fx);
      const float wy = dy ? fy : (1.f - fy);
      const bool valid = ((unsigned)xx < 128u) & ((unsigned)yy < 128u);
      float w = valid ? (wx * wy * aw) : 0.f;
      const int xc = min(max(xx, 0), 127), yc = min(max(yy, 0), 127);
      const ushort* vr = vb + ((size_t)(yc * 128 + xc) * CH + h * 32 + dh * 16);
      uint4 q0 = *(const uint4*)vr;
      uint4 q1 = *(const uint4*)(vr + 8);
      const unsigned* qw0 = (const unsigned*)&q0;
      const unsigned* qw1 = (const unsigned*)&q1;
      #pragma unroll
      for (int ww = 0; ww < 4; ++ww) {
        acc[2 * ww + 0] = fmaf(w, bfl(qw0[ww]), acc[2 * ww + 0]);
        acc[2 * ww + 1] = fmaf(w, bfh(qw0[ww]), acc[2 * ww + 1]);
        acc[8 + 2 * ww + 0] = fmaf(w, bfl(qw1[ww]), acc[8 + 2 * ww + 0]);
        acc[8 + 2 * ww + 1] = fmaf(w, bfh(qw1[ww]), acc[8 + 2 * ww + 1]);
      }
    }
  }
  unsigned r[8];
  #pragma unroll
  for (int k = 0; k < 8; ++k)
    r[k] = (unsigned)f2bf(acc[2 * k]) | ((unsigned)f2bf(acc[2 * k + 1]) << 16);
  ushort* dst = out + (size_t)pg * CH + h * 32 + dh * 16;
  *(uint4*)dst = *(uint4*)&r[0];
  *(uint4*)(dst + 8) = *(uint4*)&r[4];
}

extern "C" void kernel_launch(void* const* d_in, const int* in_sizes, int n_in,
                              void* d_out, int out_size, void* d_ws, size_t ws_size,
                              hipStream_t stream)
{
  const float* xt     = (const float*)d_in[0];
  const float* xt_1   = (const float*)d_in[1];
  const float* W_in1  = (const float*)d_in[2];
  const float* b_in1  = (const float*)d_in[3];
  const float* W_in2  = (const float*)d_in[4];
  const float* b_in2  = (const float*)d_in[5];
  const float* Wv     = (const float*)d_in[6];
  const float* bv     = (const float*)d_in[7];
  const float* Ws     = (const float*)d_in[8];
  const float* bs_off = (const float*)d_in[9];
  const float* Wa     = (const float*)d_in[10];
  const float* ba     = (const float*)d_in[11];
  const float* Wo     = (const float*)d_in[12];
  const float* bo     = (const float*)d_in[13];
  const float* Wt1    = (const float*)d_in[14];
  const float* bt1    = (const float*)d_in[15];
  const float* Wt2    = (const float*)d_in[16];
  const float* bt2    = (const float*)d_in[17];
  const float* Wout   = (const float*)d_in[18];
  const float* bout   = (const float*)d_in[19];

  char* ws = (char*)d_ws;
  const size_t SLOT = (size_t)BATCH * PIX * CH * 2;          // 16.78 MB
  const size_t SAB  = (size_t)BATCH * PIX * 192 * 4;         // 25.17 MB
  ushort* s0 = (ushort*)(ws + 0 * SLOT);   // xt_pm  -> xt_star
  ushort* s1 = (ushort*)(ws + 1 * SLOT);   // xt1_pm -> h1
  ushort* s2 = (ushort*)(ws + 2 * SLOT);   // x1 (live to end)
  ushort* s3 = (ushort*)(ws + 3 * SLOT);   // value  -> tg
  ushort* s4 = (ushort*)(ws + 4 * SLOT);   // msda_out
  float*  sa = (float*)(ws + 5 * SLOT);    // [B][P][192] offs+attn
  char* wbase = ws + 5 * SLOT + SAB;
  ushort* wb  = (ushort*)wbase;            // 1472x256 bf16
  ushort* wvp = (ushort*)(wbase + (size_t)1472 * 256 * 2);   // 256x256 bf16
  float* bsa  = (float*)(wbase + (size_t)1472 * 256 * 2 + (size_t)256 * 256 * 2);
  float* bvp  = bsa + 192;

  ushort* wb_in1 = wb;
  ushort* wb_o   = wb + 65536;
  ushort* wb_t1  = wb + 131072;
  ushort* wb_t2  = wb + 196608;
  ushort* wb_out = wb + 262144;
  ushort* wb_sa  = wb + 327680;            // 192 rows: Ws then Wa

  dim3 blk(256);
  dim3 gT(PIX / 32, CH / 32, BATCH);
  dim3 gF(PIX / 128, 4, BATCH);            // Cout=256
  dim3 gS(PIX / 128, 3, BATCH);            // Cout=192
  const size_t OBS = (size_t)PIX * CH;     // pm bf16 batch stride (elems)

  wprep_k<<<1473, blk, 0, stream>>>(W_in1, Wo, Wt1, Wt2, Wout, Ws, Wa, bs_off, ba, wb, bsa);
  wvcomp_k<<<256, blk, 0, stream>>>(Wv, W_in2, b_in2, bv, wvp, bvp);
  tconv_k<<<gT, blk, 0, stream>>>(xt, s0);
  tconv_k<<<gT, blk, 0, stream>>>(xt_1, s1);

  gemm2_k<0, false, 0><<<gF, blk, 0, stream>>>(s0, nullptr, wb_in1, b_in1, s2, CH, OBS);          // x1
  gemm2_k<0, false, 0><<<gF, blk, 0, stream>>>(s1, nullptr, wvp, bvp, s3, CH, OBS);               // value
  gemm2_k<0, false, 2><<<gS, blk, 0, stream>>>(s2, nullptr, wb_sa, bsa, sa, 192, (size_t)PIX * 192); // offs+attn
  msda_k<<<dim3((BATCH * PIX * 16) / 256), blk, 0, stream>>>(s3, sa, s4);
  gemm2_k<0, false, 0><<<gF, blk, 0, stream>>>(s4, nullptr, wb_o, bo, s0, CH, OBS);               // xt_star
  gemm2_k<1, true , 0><<<gF, blk, 0, stream>>>(s0, s2, wb_t1, bt1, s1, CH, OBS);                  // h1
  gemm2_k<0, false, 0><<<gF, blk, 0, stream>>>(s1, nullptr, wb_t2, bt2, s3, CH, OBS);             // tg
  gemm2_k<2, true , 1><<<gF, blk, 0, stream>>>(s3, s2, wb_out, bout, d_out, PIX, (size_t)CH * PIX); // out
}